// Round 1
// baseline (1687.201 us; speedup 1.0000x reference)
//
#include <hip/hip_runtime.h>

#define DF 128

__device__ __forceinline__ unsigned enc_f(float x) {
  unsigned b = __float_as_uint(x);
  return (b & 0x80000000u) ? ~b : (b | 0x80000000u);
}
__device__ __forceinline__ float dec_f(unsigned u) {
  unsigned b = (u & 0x80000000u) ? (u & 0x7fffffffu) : ~u;
  return __uint_as_float(b);
}
__device__ __forceinline__ float lrelu(float x) { return x > 0.0f ? x : 0.01f * x; }

// ---------------------------------------------------------------------------
// init: zero segsum, h_nb; segmax encoded -inf (= 0 in ordered-uint encoding)
// ---------------------------------------------------------------------------
__global__ __launch_bounds__(256) void k_init(float* __restrict__ segsum,
                                              unsigned* __restrict__ segmax,
                                              float* __restrict__ h_nb, int N) {
  int i = blockIdx.x * 256 + threadIdx.x;
  if (i < N * DF) h_nb[i] = 0.0f;
  if (i < N) { segsum[i] = 0.0f; segmax[i] = 0u; }
}

// ---------------------------------------------------------------------------
// proj GEMM: out[n,f] = sum_k h[n,k] * W_r[k,f]
// 32-row x 128-col tile per block, 4x4 register blocking, W_r + A tile in LDS.
// grid.y indexes relation (full mode) or 1 (per-r mode, r passed via r0).
// ---------------------------------------------------------------------------
__global__ __launch_bounds__(256) void proj_gemm(const float* __restrict__ h,
                                                 const float* __restrict__ relW,
                                                 float* __restrict__ proj, int N,
                                                 int r0, long long out_rstride) {
  __shared__ float Bs[DF * DF];   // 64 KB: W_r[k][f]
  __shared__ float As[32 * DF];   // 16 KB: A[row][k]
  int r = r0 + blockIdx.y;
  const float* W = relW + (size_t)r * DF * DF;
  float* out = proj + (size_t)blockIdx.y * out_rstride;
  int n0 = blockIdx.x * 32;
  int t = threadIdx.x;

  // stage W_r: 4096 float4, coalesced
#pragma unroll
  for (int i = 0; i < 16; i++) {
    int idx = i * 256 + t;
    ((float4*)Bs)[idx] = ((const float4*)W)[idx];
  }
  // stage A: 1024 float4
#pragma unroll
  for (int i = 0; i < 4; i++) {
    int idx = i * 256 + t;
    int row = idx >> 5, c4 = idx & 31;
    int n = n0 + row;
    float4 v = make_float4(0.f, 0.f, 0.f, 0.f);
    if (n < N) v = ((const float4*)(h + (size_t)n * DF))[c4];
    ((float4*)As)[idx] = v;
  }
  __syncthreads();

  int tc = t & 31, tr = t >> 5;   // cols tc*4.., rows tr*4..
  float acc[4][4] = {};
#pragma unroll 4
  for (int k = 0; k < DF; k++) {
    float a0 = As[(tr * 4 + 0) * DF + k];
    float a1 = As[(tr * 4 + 1) * DF + k];
    float a2 = As[(tr * 4 + 2) * DF + k];
    float a3 = As[(tr * 4 + 3) * DF + k];
    float4 b = *(const float4*)&Bs[k * DF + tc * 4];
    acc[0][0] += a0 * b.x; acc[0][1] += a0 * b.y; acc[0][2] += a0 * b.z; acc[0][3] += a0 * b.w;
    acc[1][0] += a1 * b.x; acc[1][1] += a1 * b.y; acc[1][2] += a1 * b.z; acc[1][3] += a1 * b.w;
    acc[2][0] += a2 * b.x; acc[2][1] += a2 * b.y; acc[2][2] += a2 * b.z; acc[2][3] += a2 * b.w;
    acc[3][0] += a3 * b.x; acc[3][1] += a3 * b.y; acc[3][2] += a3 * b.z; acc[3][3] += a3 * b.w;
  }
#pragma unroll
  for (int i = 0; i < 4; i++) {
    int n = n0 + tr * 4 + i;
    if (n < N) {
      float4 o = make_float4(acc[i][0], acc[i][1], acc[i][2], acc[i][3]);
      *(float4*)&out[(size_t)n * DF + tc * 4] = o;
    }
  }
}

// ---------------------------------------------------------------------------
// att: one wave per edge. att[e] = dot(t_r, tanh(h_r + efeat[e]));
// atomicMax the dst segment max (ordered-uint encoding).
// rsel >= 0: only process edges with etype==rsel (per-r mode, rstride==0).
// ---------------------------------------------------------------------------
__global__ __launch_bounds__(256) void att_kernel(const float* __restrict__ proj,
                                                  const float* __restrict__ efeat,
                                                  const int* __restrict__ src,
                                                  const int* __restrict__ dst,
                                                  const int* __restrict__ etype,
                                                  float* __restrict__ att,
                                                  unsigned* __restrict__ segmax,
                                                  int E, long long rstride, int rsel) {
  int gid = blockIdx.x * 256 + threadIdx.x;
  int e = gid >> 6, lane = gid & 63;
  if (e >= E) return;
  int rt = etype[e];
  if (rsel >= 0 && rt != rsel) return;
  int s = src[e], d = dst[e];
  const float* pb = proj + (size_t)rt * (size_t)rstride;
  float2 tv = ((const float2*)(pb + (size_t)s * DF))[lane];
  float2 hv = ((const float2*)(pb + (size_t)d * DF))[lane];
  float2 ev = ((const float2*)(efeat + (size_t)e * DF))[lane];
  float p = tv.x * tanhf(hv.x + ev.x) + tv.y * tanhf(hv.y + ev.y);
  p += __shfl_down(p, 32);
  p += __shfl_down(p, 16);
  p += __shfl_down(p, 8);
  p += __shfl_down(p, 4);
  p += __shfl_down(p, 2);
  p += __shfl_down(p, 1);
  if (lane == 0) {
    att[e] = p;
    atomicMax(segmax + d, enc_f(p));
  }
}

// ---------------------------------------------------------------------------
// scatter: ex = exp(att - segmax[dst]); segsum[dst] += ex;
// h_nb[dst,:] += h[src,:] * ex  (unnormalized; divided by segsum later)
// ---------------------------------------------------------------------------
__global__ __launch_bounds__(256) void scatter_kernel(const float* __restrict__ nfeat,
                                                      const int* __restrict__ src,
                                                      const int* __restrict__ dst,
                                                      const float* __restrict__ att,
                                                      const unsigned* __restrict__ segmax,
                                                      float* __restrict__ segsum,
                                                      float* __restrict__ h_nb, int E) {
  int gid = blockIdx.x * 256 + threadIdx.x;
  int e = gid >> 6, lane = gid & 63;
  if (e >= E) return;
  int s = src[e], d = dst[e];
  float m = dec_f(segmax[d]);
  float ex = expf(att[e] - m);
  if (lane == 0) atomicAdd(segsum + d, ex);
  float2 hv = ((const float2*)(nfeat + (size_t)s * DF))[lane];
  float* hb = h_nb + (size_t)d * DF + lane * 2;
  atomicAdd(hb + 0, hv.x * ex);
  atomicAdd(hb + 1, hv.y * ex);
}

// ---------------------------------------------------------------------------
// output GEMM: out[n,j] (op)= lrelu( sum_d A[n,d] * W[j,d] )
// A = h + h_nb/segsum (mode 0, assign) or h * h_nb/segsum (mode 1, +=)
// ---------------------------------------------------------------------------
__global__ __launch_bounds__(256) void out_gemm(const float* __restrict__ nfeat,
                                                const float* __restrict__ h_nb,
                                                const float* __restrict__ segsum,
                                                const float* __restrict__ W,
                                                float* __restrict__ out, int N, int mode) {
  __shared__ float Ws[DF * 129];  // W[j][d], padded stride 129 (bank spread)
  __shared__ float As[32 * DF];
  int n0 = blockIdx.x * 32;
  int t = threadIdx.x;
#pragma unroll
  for (int i = 0; i < 16; i++) {
    int idx = i * 256 + t;
    int j = idx >> 5, d4 = idx & 31;
    float4 v = ((const float4*)W)[idx];
    int b = j * 129 + d4 * 4;
    Ws[b + 0] = v.x; Ws[b + 1] = v.y; Ws[b + 2] = v.z; Ws[b + 3] = v.w;
  }
#pragma unroll
  for (int i = 0; i < 4; i++) {
    int idx = i * 256 + t;
    int row = idx >> 5, c4 = idx & 31;
    int n = n0 + row;
    float4 a = make_float4(0.f, 0.f, 0.f, 0.f);
    if (n < N) {
      float4 hv = ((const float4*)(nfeat + (size_t)n * DF))[c4];
      float4 bv = ((const float4*)(h_nb + (size_t)n * DF))[c4];
      float ss = segsum[n];
      float inv = ss > 0.0f ? 1.0f / ss : 0.0f;
      float n0v = bv.x * inv, n1v = bv.y * inv, n2v = bv.z * inv, n3v = bv.w * inv;
      if (mode == 0) { a = make_float4(hv.x + n0v, hv.y + n1v, hv.z + n2v, hv.w + n3v); }
      else           { a = make_float4(hv.x * n0v, hv.y * n1v, hv.z * n2v, hv.w * n3v); }
    }
    ((float4*)As)[idx] = a;
  }
  __syncthreads();

  int tc = t & 31, tr = t >> 5;
  float acc[4][4] = {};
#pragma unroll 4
  for (int k = 0; k < DF; k++) {
    float a0 = As[(tr * 4 + 0) * DF + k];
    float a1 = As[(tr * 4 + 1) * DF + k];
    float a2 = As[(tr * 4 + 2) * DF + k];
    float a3 = As[(tr * 4 + 3) * DF + k];
    float w0 = Ws[(tc * 4 + 0) * 129 + k];
    float w1 = Ws[(tc * 4 + 1) * 129 + k];
    float w2 = Ws[(tc * 4 + 2) * 129 + k];
    float w3 = Ws[(tc * 4 + 3) * 129 + k];
    acc[0][0] += a0 * w0; acc[0][1] += a0 * w1; acc[0][2] += a0 * w2; acc[0][3] += a0 * w3;
    acc[1][0] += a1 * w0; acc[1][1] += a1 * w1; acc[1][2] += a1 * w2; acc[1][3] += a1 * w3;
    acc[2][0] += a2 * w0; acc[2][1] += a2 * w1; acc[2][2] += a2 * w2; acc[2][3] += a2 * w3;
    acc[3][0] += a3 * w0; acc[3][1] += a3 * w1; acc[3][2] += a3 * w2; acc[3][3] += a3 * w3;
  }
#pragma unroll
  for (int i = 0; i < 4; i++) {
    int n = n0 + tr * 4 + i;
    if (n < N) {
      float4 o = make_float4(lrelu(acc[i][0]), lrelu(acc[i][1]),
                             lrelu(acc[i][2]), lrelu(acc[i][3]));
      float4* po = (float4*)&out[(size_t)n * DF + tc * 4];
      if (mode == 0) {
        *po = o;
      } else {
        float4 old = *po;
        *po = make_float4(old.x + o.x, old.y + o.y, old.z + o.z, old.w + o.w);
      }
    }
  }
}

extern "C" void kernel_launch(void* const* d_in, const int* in_sizes, int n_in,
                              void* d_out, int out_size, void* d_ws, size_t ws_size,
                              hipStream_t stream) {
  const float* nfeat  = (const float*)d_in[0];
  const float* efeat  = (const float*)d_in[1];
  const float* relW   = (const float*)d_in[2];
  const float* W_res  = (const float*)d_in[3];
  const float* W_res2 = (const float*)d_in[4];
  const int*   src    = (const int*)d_in[5];
  const int*   dst    = (const int*)d_in[6];
  const int*   etype  = (const int*)d_in[7];
  float* out = (float*)d_out;

  int N = in_sizes[0] / DF;
  int E = in_sizes[5];
  int R = in_sizes[2] / (DF * DF);

  // workspace layout (all 16B-aligned offsets)
  char* w = (char*)d_ws;
  float*    att    = (float*)w;    w += (size_t)E * 4;
  unsigned* segmax = (unsigned*)w; w += (size_t)N * 4;
  float*    segsum = (float*)w;    w += (size_t)N * 4;
  float*    h_nb   = (float*)w;    w += (size_t)N * DF * 4;
  float*    proj   = (float*)w;
  size_t used = (size_t)(w - (char*)d_ws);
  size_t proj_full_bytes = (size_t)R * N * DF * 4;
  bool full = (ws_size >= used + proj_full_bytes);

  int nd_blocks  = (N * DF + 255) / 256;
  int row_tiles  = (N + 31) / 32;
  int att_blocks = (E + 3) / 4;   // one wave (64 lanes) per edge, 4 waves/block

  k_init<<<nd_blocks, 256, 0, stream>>>(segsum, segmax, h_nb, N);

  if (full) {
    proj_gemm<<<dim3(row_tiles, R), 256, 0, stream>>>(nfeat, relW, proj, N, 0,
                                                      (long long)N * DF);
    att_kernel<<<att_blocks, 256, 0, stream>>>(proj, efeat, src, dst, etype, att,
                                               segmax, E, (long long)N * DF, -1);
  } else {
    for (int r = 0; r < R; r++) {
      proj_gemm<<<dim3(row_tiles, 1), 256, 0, stream>>>(nfeat, relW, proj, N, r, 0);
      att_kernel<<<att_blocks, 256, 0, stream>>>(proj, efeat, src, dst, etype, att,
                                                 segmax, E, 0, r);
    }
  }

  scatter_kernel<<<att_blocks, 256, 0, stream>>>(nfeat, src, dst, att, segmax,
                                                 segsum, h_nb, E);
  out_gemm<<<row_tiles, 256, 0, stream>>>(nfeat, h_nb, segsum, W_res,  out, N, 0);
  out_gemm<<<row_tiles, 256, 0, stream>>>(nfeat, h_nb, segsum, W_res2, out, N, 1);
}

// Round 2
// 1283.878 us; speedup vs baseline: 1.3141x; 1.3141x over previous
//
#include <hip/hip_runtime.h>

#define DF 128

__device__ __forceinline__ float lrelu(float x) { return x > 0.0f ? x : 0.01f * x; }

// ---------------------------------------------------------------------------
// init: zero deg + cur counters
// ---------------------------------------------------------------------------
__global__ __launch_bounds__(256) void k_zero(int* __restrict__ deg,
                                              int* __restrict__ cur, int N) {
  int i = blockIdx.x * 256 + threadIdx.x;
  if (i < N) { deg[i] = 0; cur[i] = 0; }
}

// histogram of dst
__global__ __launch_bounds__(256) void k_hist(const int* __restrict__ dst,
                                              int* __restrict__ deg, int E) {
  int e = blockIdx.x * 256 + threadIdx.x;
  if (e < E) atomicAdd(&deg[dst[e]], 1);
}

// per-block exclusive scan (256 elems/block) + block sums
__global__ __launch_bounds__(256) void k_scan1(const int* __restrict__ deg,
                                               int* __restrict__ excl,
                                               int* __restrict__ bsum, int N) {
  __shared__ int s[256];
  int tid = threadIdx.x;
  int i = blockIdx.x * 256 + tid;
  int v = (i < N) ? deg[i] : 0;
  s[tid] = v;
  __syncthreads();
  for (int d = 1; d < 256; d <<= 1) {
    int t = (tid >= d) ? s[tid - d] : 0;
    __syncthreads();
    s[tid] += t;
    __syncthreads();
  }
  int incl = s[tid];
  if (i < N) excl[i] = incl - v;
  if (tid == 255) bsum[blockIdx.x] = incl;
}

// single-block exclusive scan of block sums (loop with carry, nb arbitrary)
__global__ __launch_bounds__(256) void k_scan2(int* __restrict__ bsum, int nb) {
  __shared__ int s[256];
  __shared__ int carry;
  int tid = threadIdx.x;
  if (tid == 0) carry = 0;
  __syncthreads();
  for (int base = 0; base < nb; base += 256) {
    int i = base + tid;
    int v = (i < nb) ? bsum[i] : 0;
    s[tid] = v;
    __syncthreads();
    for (int d = 1; d < 256; d <<= 1) {
      int t = (tid >= d) ? s[tid - d] : 0;
      __syncthreads();
      s[tid] += t;
      __syncthreads();
    }
    int incl = s[tid];
    int c = carry;
    if (i < nb) bsum[i] = incl - v + c;
    __syncthreads();
    if (tid == 255) carry = c + s[255];
    __syncthreads();
  }
}

// add block offsets -> off[i]; off[N] = E
__global__ __launch_bounds__(256) void k_scan3(const int* __restrict__ excl,
                                               const int* __restrict__ bsum,
                                               int* __restrict__ off, int N, int E) {
  int i = blockIdx.x * 256 + threadIdx.x;
  if (i < N) off[i] = excl[i] + bsum[blockIdx.x];
  if (i == 0) off[N] = E;
}

// fill CSR edge list
__global__ __launch_bounds__(256) void k_fill(const int* __restrict__ dst,
                                              const int* __restrict__ off,
                                              int* __restrict__ cur,
                                              int* __restrict__ eid, int E) {
  int e = blockIdx.x * 256 + threadIdx.x;
  if (e >= E) return;
  int d = dst[e];
  int p = atomicAdd(&cur[d], 1);
  eid[off[d] + p] = e;
}

// ---------------------------------------------------------------------------
// proj GEMM: out[n,f] = sum_k h[n,k] * W_r[k,f]
// ---------------------------------------------------------------------------
__global__ __launch_bounds__(256) void proj_gemm(const float* __restrict__ h,
                                                 const float* __restrict__ relW,
                                                 float* __restrict__ proj, int N,
                                                 int r0, long long out_rstride) {
  __shared__ float Bs[DF * DF];
  __shared__ float As[32 * DF];
  int r = r0 + blockIdx.y;
  const float* W = relW + (size_t)r * DF * DF;
  float* out = proj + (size_t)blockIdx.y * out_rstride;
  int n0 = blockIdx.x * 32;
  int t = threadIdx.x;

#pragma unroll
  for (int i = 0; i < 16; i++) {
    int idx = i * 256 + t;
    ((float4*)Bs)[idx] = ((const float4*)W)[idx];
  }
#pragma unroll
  for (int i = 0; i < 4; i++) {
    int idx = i * 256 + t;
    int row = idx >> 5, c4 = idx & 31;
    int n = n0 + row;
    float4 v = make_float4(0.f, 0.f, 0.f, 0.f);
    if (n < N) v = ((const float4*)(h + (size_t)n * DF))[c4];
    ((float4*)As)[idx] = v;
  }
  __syncthreads();

  int tc = t & 31, tr = t >> 5;
  float acc[4][4] = {};
#pragma unroll 4
  for (int k = 0; k < DF; k++) {
    float a0 = As[(tr * 4 + 0) * DF + k];
    float a1 = As[(tr * 4 + 1) * DF + k];
    float a2 = As[(tr * 4 + 2) * DF + k];
    float a3 = As[(tr * 4 + 3) * DF + k];
    float4 b = *(const float4*)&Bs[k * DF + tc * 4];
    acc[0][0] += a0 * b.x; acc[0][1] += a0 * b.y; acc[0][2] += a0 * b.z; acc[0][3] += a0 * b.w;
    acc[1][0] += a1 * b.x; acc[1][1] += a1 * b.y; acc[1][2] += a1 * b.z; acc[1][3] += a1 * b.w;
    acc[2][0] += a2 * b.x; acc[2][1] += a2 * b.y; acc[2][2] += a2 * b.z; acc[2][3] += a2 * b.w;
    acc[3][0] += a3 * b.x; acc[3][1] += a3 * b.y; acc[3][2] += a3 * b.z; acc[3][3] += a3 * b.w;
  }
#pragma unroll
  for (int i = 0; i < 4; i++) {
    int n = n0 + tr * 4 + i;
    if (n < N) {
      float4 o = make_float4(acc[i][0], acc[i][1], acc[i][2], acc[i][3]);
      *(float4*)&out[(size_t)n * DF + tc * 4] = o;
    }
  }
}

// ---------------------------------------------------------------------------
// att: one wave per edge. att[e] = dot(t_r, tanh(h_r + efeat[e])). No atomics.
// ---------------------------------------------------------------------------
__global__ __launch_bounds__(256) void att_kernel(const float* __restrict__ proj,
                                                  const float* __restrict__ efeat,
                                                  const int* __restrict__ src,
                                                  const int* __restrict__ dst,
                                                  const int* __restrict__ etype,
                                                  float* __restrict__ att,
                                                  int E, long long rstride, int rsel) {
  int gid = blockIdx.x * 256 + threadIdx.x;
  int e = gid >> 6, lane = gid & 63;
  if (e >= E) return;
  int rt = etype[e];
  if (rsel >= 0 && rt != rsel) return;
  int s = src[e], d = dst[e];
  const float* pb = proj + (size_t)rt * (size_t)rstride;
  float2 tv = ((const float2*)(pb + (size_t)s * DF))[lane];
  float2 hv = ((const float2*)(pb + (size_t)d * DF))[lane];
  float2 ev = ((const float2*)(efeat + (size_t)e * DF))[lane];
  float p = tv.x * tanhf(hv.x + ev.x) + tv.y * tanhf(hv.y + ev.y);
  p += __shfl_down(p, 32);
  p += __shfl_down(p, 16);
  p += __shfl_down(p, 8);
  p += __shfl_down(p, 4);
  p += __shfl_down(p, 2);
  p += __shfl_down(p, 1);
  if (lane == 0) att[e] = p;
}

// ---------------------------------------------------------------------------
// gather: one wave per dst node. Segment softmax + weighted sum, no atomics.
// h_nb written already normalized.
// ---------------------------------------------------------------------------
__global__ __launch_bounds__(256) void gather_kernel(const int* __restrict__ eid,
                                                     const int* __restrict__ off,
                                                     const int* __restrict__ src,
                                                     const float* __restrict__ att,
                                                     const float* __restrict__ nfeat,
                                                     float* __restrict__ h_nb, int N) {
  int node = blockIdx.x * 4 + (threadIdx.x >> 6);
  int lane = threadIdx.x & 63;
  if (node >= N) return;
  int s0 = off[node], s1 = off[node + 1];

  // pass 1: segment max (lanes stride over edges)
  float m = -3.402823466e+38f;
  for (int j = s0 + lane; j < s1; j += 64) {
    float a = att[eid[j]];
    m = fmaxf(m, a);
  }
#pragma unroll
  for (int d = 32; d >= 1; d >>= 1) m = fmaxf(m, __shfl_xor(m, d));

  // pass 2: accumulate exp-weighted src features
  float2 acc = make_float2(0.f, 0.f);
  float ssum = 0.f;
  for (int j = s0; j < s1; j++) {
    int e = eid[j];
    float ex = expf(att[e] - m);
    int sv = src[e];
    float2 hv = ((const float2*)(nfeat + (size_t)sv * DF))[lane];
    acc.x += hv.x * ex;
    acc.y += hv.y * ex;
    ssum += ex;
  }
  float inv = (s1 > s0) ? 1.0f / ssum : 0.0f;
  float2 o = make_float2(acc.x * inv, acc.y * inv);
  ((float2*)(h_nb + (size_t)node * DF))[lane] = o;
}

// ---------------------------------------------------------------------------
// output GEMM: out[n,j] (op)= lrelu( sum_d A[n,d] * W[j,d] )
// A = h + h_nb (mode 0, assign) or h * h_nb (mode 1, +=); h_nb pre-normalized.
// ---------------------------------------------------------------------------
__global__ __launch_bounds__(256) void out_gemm(const float* __restrict__ nfeat,
                                                const float* __restrict__ h_nb,
                                                const float* __restrict__ W,
                                                float* __restrict__ out, int N, int mode) {
  __shared__ float Ws[DF * 129];
  __shared__ float As[32 * DF];
  int n0 = blockIdx.x * 32;
  int t = threadIdx.x;
#pragma unroll
  for (int i = 0; i < 16; i++) {
    int idx = i * 256 + t;
    int j = idx >> 5, d4 = idx & 31;
    float4 v = ((const float4*)W)[idx];
    int b = j * 129 + d4 * 4;
    Ws[b + 0] = v.x; Ws[b + 1] = v.y; Ws[b + 2] = v.z; Ws[b + 3] = v.w;
  }
#pragma unroll
  for (int i = 0; i < 4; i++) {
    int idx = i * 256 + t;
    int row = idx >> 5, c4 = idx & 31;
    int n = n0 + row;
    float4 a = make_float4(0.f, 0.f, 0.f, 0.f);
    if (n < N) {
      float4 hv = ((const float4*)(nfeat + (size_t)n * DF))[c4];
      float4 bv = ((const float4*)(h_nb + (size_t)n * DF))[c4];
      if (mode == 0) a = make_float4(hv.x + bv.x, hv.y + bv.y, hv.z + bv.z, hv.w + bv.w);
      else           a = make_float4(hv.x * bv.x, hv.y * bv.y, hv.z * bv.z, hv.w * bv.w);
    }
    ((float4*)As)[idx] = a;
  }
  __syncthreads();

  int tc = t & 31, tr = t >> 5;
  float acc[4][4] = {};
#pragma unroll 4
  for (int k = 0; k < DF; k++) {
    float a0 = As[(tr * 4 + 0) * DF + k];
    float a1 = As[(tr * 4 + 1) * DF + k];
    float a2 = As[(tr * 4 + 2) * DF + k];
    float a3 = As[(tr * 4 + 3) * DF + k];
    float w0 = Ws[(tc * 4 + 0) * 129 + k];
    float w1 = Ws[(tc * 4 + 1) * 129 + k];
    float w2 = Ws[(tc * 4 + 2) * 129 + k];
    float w3 = Ws[(tc * 4 + 3) * 129 + k];
    acc[0][0] += a0 * w0; acc[0][1] += a0 * w1; acc[0][2] += a0 * w2; acc[0][3] += a0 * w3;
    acc[1][0] += a1 * w0; acc[1][1] += a1 * w1; acc[1][2] += a1 * w2; acc[1][3] += a1 * w3;
    acc[2][0] += a2 * w0; acc[2][1] += a2 * w1; acc[2][2] += a2 * w2; acc[2][3] += a2 * w3;
    acc[3][0] += a3 * w0; acc[3][1] += a3 * w1; acc[3][2] += a3 * w2; acc[3][3] += a3 * w3;
  }
#pragma unroll
  for (int i = 0; i < 4; i++) {
    int n = n0 + tr * 4 + i;
    if (n < N) {
      float4 o = make_float4(lrelu(acc[i][0]), lrelu(acc[i][1]),
                             lrelu(acc[i][2]), lrelu(acc[i][3]));
      float4* po = (float4*)&out[(size_t)n * DF + tc * 4];
      if (mode == 0) {
        *po = o;
      } else {
        float4 old = *po;
        *po = make_float4(old.x + o.x, old.y + o.y, old.z + o.z, old.w + o.w);
      }
    }
  }
}

extern "C" void kernel_launch(void* const* d_in, const int* in_sizes, int n_in,
                              void* d_out, int out_size, void* d_ws, size_t ws_size,
                              hipStream_t stream) {
  const float* nfeat  = (const float*)d_in[0];
  const float* efeat  = (const float*)d_in[1];
  const float* relW   = (const float*)d_in[2];
  const float* W_res  = (const float*)d_in[3];
  const float* W_res2 = (const float*)d_in[4];
  const int*   src    = (const int*)d_in[5];
  const int*   dst    = (const int*)d_in[6];
  const int*   etype  = (const int*)d_in[7];
  float* out = (float*)d_out;

  int N = in_sizes[0] / DF;
  int E = in_sizes[5];
  int R = in_sizes[2] / (DF * DF);

  int nblk256 = (N + 255) / 256;       // scan blocks over N
  int eblk256 = (E + 255) / 256;

  // workspace layout
  char* w = (char*)d_ws;
  float* att  = (float*)w;  w += (size_t)E * 4;
  int*   eid  = (int*)w;    w += (size_t)E * 4;
  int*   deg  = (int*)w;    w += (size_t)N * 4;
  int*   excl = (int*)w;    w += (size_t)N * 4;
  int*   cur  = (int*)w;    w += (size_t)N * 4;
  int*   off  = (int*)w;    w += (size_t)(N + 1) * 4;
  int*   bsum = (int*)w;    w += (size_t)(nblk256 + 1) * 4;
  w = (char*)(((size_t)w + 255) & ~(size_t)255);
  float* h_nb = (float*)w;  w += (size_t)N * DF * 4;
  float* proj = (float*)w;
  size_t used = (size_t)(w - (char*)d_ws);
  size_t proj_full_bytes = (size_t)R * N * DF * 4;
  bool full = (ws_size >= used + proj_full_bytes);

  int row_tiles  = (N + 31) / 32;
  int att_blocks = (E + 3) / 4;        // one wave per edge, 4 waves/block
  int gat_blocks = (N + 3) / 4;        // one wave per node

  // --- CSR build (independent of proj; overlaps nothing but cheap) ---
  k_zero<<<nblk256, 256, 0, stream>>>(deg, cur, N);
  k_hist<<<eblk256, 256, 0, stream>>>(dst, deg, E);
  k_scan1<<<nblk256, 256, 0, stream>>>(deg, excl, bsum, N);
  k_scan2<<<1, 256, 0, stream>>>(bsum, nblk256);
  k_scan3<<<nblk256, 256, 0, stream>>>(excl, bsum, off, N, E);
  k_fill<<<eblk256, 256, 0, stream>>>(dst, off, cur, eid, E);

  // --- projection + attention logits ---
  if (full) {
    proj_gemm<<<dim3(row_tiles, R), 256, 0, stream>>>(nfeat, relW, proj, N, 0,
                                                      (long long)N * DF);
    att_kernel<<<att_blocks, 256, 0, stream>>>(proj, efeat, src, dst, etype, att,
                                               E, (long long)N * DF, -1);
  } else {
    for (int r = 0; r < R; r++) {
      proj_gemm<<<dim3(row_tiles, 1), 256, 0, stream>>>(nfeat, relW, proj, N, r, 0);
      att_kernel<<<att_blocks, 256, 0, stream>>>(proj, efeat, src, dst, etype, att,
                                                 E, 0, r);
    }
  }

  // --- segment softmax + message aggregation (no atomics) ---
  gather_kernel<<<gat_blocks, 256, 0, stream>>>(eid, off, src, att, nfeat, h_nb, N);

  // --- output projections ---
  out_gemm<<<row_tiles, 256, 0, stream>>>(nfeat, h_nb, W_res,  out, N, 0);
  out_gemm<<<row_tiles, 256, 0, stream>>>(nfeat, h_nb, W_res2, out, N, 1);
}

// Round 3
// 1098.554 us; speedup vs baseline: 1.5358x; 1.1687x over previous
//
#include <hip/hip_runtime.h>

#define DF 128

typedef __attribute__((ext_vector_type(8))) short short8;
typedef __attribute__((ext_vector_type(4))) float floatx4;

__device__ __forceinline__ float lrelu(float x) { return x > 0.0f ? x : 0.01f * x; }

// round-to-nearest-even fp32 -> bf16 bits
__device__ __forceinline__ unsigned short f2bf(float x) {
  unsigned u = __float_as_uint(x);
  unsigned r = (u >> 16) & 1u;
  return (unsigned short)((u + 0x7fffu + r) >> 16);
}
__device__ __forceinline__ float bf2f(unsigned short h) {
  return __uint_as_float(((unsigned)h) << 16);
}

// ---------------------------------------------------------------------------
// convert nfeat -> Ahi/Alo bf16 row-major [N*128]
// ---------------------------------------------------------------------------
__global__ __launch_bounds__(256) void k_convA(const float* __restrict__ x,
                                               unsigned short* __restrict__ hi,
                                               unsigned short* __restrict__ lo,
                                               int total4) {
  int i = blockIdx.x * 256 + threadIdx.x;
  if (i >= total4) return;
  float4 v = ((const float4*)x)[i];
  ushort4 h, l;
  h.x = f2bf(v.x); l.x = f2bf(v.x - bf2f(h.x));
  h.y = f2bf(v.y); l.y = f2bf(v.y - bf2f(h.y));
  h.z = f2bf(v.z); l.z = f2bf(v.z - bf2f(h.z));
  h.w = f2bf(v.w); l.w = f2bf(v.w - bf2f(h.w));
  ((ushort4*)hi)[i] = h;
  ((ushort4*)lo)[i] = l;
}

// ---------------------------------------------------------------------------
// convert relW -> fragment-swizzled bf16 hi/lo.
// Layout per relation (32768 ushorts): [hi(16384) | lo(16384)], each
// [ntile(8)][kiter(4)][lane(64)][j(8)] where k = kiter*32+(lane>>4)*8+j,
// n = ntile*16+(lane&15), value = W[r][k][n].
// ---------------------------------------------------------------------------
__global__ __launch_bounds__(256) void k_convW(const float* __restrict__ W,
                                               unsigned short* __restrict__ Wsw,
                                               int R) {
  int g = blockIdx.x * 256 + threadIdx.x;           // group id: (r, nt, kit, lane)
  int total = R * 8 * 4 * 64;
  if (g >= total) return;
  int lane = g & 63;
  int kit  = (g >> 6) & 3;
  int nt   = (g >> 8) & 7;
  int r    = g >> 11;
  int n = nt * 16 + (lane & 15);
  int kbase = kit * 32 + (lane >> 4) * 8;
  unsigned short hbuf[8], lbuf[8];
#pragma unroll
  for (int j = 0; j < 8; j++) {
    float x = W[((size_t)r * DF + (kbase + j)) * DF + n];
    unsigned short h = f2bf(x);
    hbuf[j] = h;
    lbuf[j] = f2bf(x - bf2f(h));
  }
  size_t base = (size_t)r * 32768 + (((nt * 4 + kit) * 64 + lane) * 8);
  ((ushort4*)(Wsw + base))[0] = *(ushort4*)&hbuf[0];
  ((ushort4*)(Wsw + base))[1] = *(ushort4*)&hbuf[4];
  ((ushort4*)(Wsw + base + 16384))[0] = *(ushort4*)&lbuf[0];
  ((ushort4*)(Wsw + base + 16384))[1] = *(ushort4*)&lbuf[4];
}

// ---------------------------------------------------------------------------
// proj MFMA GEMM (split-bf16, ~fp32 accurate): proj[r][n][f] = sum_k h[n][k]W[r][k][f]
// 128 rows/block, 4 waves, each wave a 32x128 slab (2x8 grid of 16x16 tiles).
// No LDS, no barriers: A frags from global (L3-resident), B frags from global
// (L2-resident, swizzled contiguous).
// ---------------------------------------------------------------------------
__global__ __launch_bounds__(256) void proj_mfma(const unsigned short* __restrict__ Ahi,
                                                 const unsigned short* __restrict__ Alo,
                                                 const unsigned short* __restrict__ Wsw,
                                                 float* __restrict__ proj, int N,
                                                 int r0, long long out_rstride) {
  int t = threadIdx.x;
  int wave = t >> 6, lane = t & 63;
  int quad = lane >> 4, l15 = lane & 15;
  int r = r0 + blockIdx.y;
  float* out = proj + (size_t)blockIdx.y * out_rstride;
  int mbase = blockIdx.x * 128 + wave * 32;

  const unsigned short* wr = Wsw + (size_t)r * 32768;

  floatx4 acc[2][8];
#pragma unroll
  for (int mt = 0; mt < 2; mt++)
#pragma unroll
    for (int nt = 0; nt < 8; nt++) acc[mt][nt] = (floatx4){0.f, 0.f, 0.f, 0.f};

  // A row addresses for the two m-tiles (clamped; OOB rows never stored)
  int row0 = mbase + l15;       if (row0 >= N) row0 = N - 1;
  int row1 = mbase + 16 + l15;  if (row1 >= N) row1 = N - 1;

#pragma unroll
  for (int kit = 0; kit < 4; kit++) {
    int kcol = kit * 32 + quad * 8;
    short8 ah0 = *(const short8*)(Ahi + (size_t)row0 * DF + kcol);
    short8 al0 = *(const short8*)(Alo + (size_t)row0 * DF + kcol);
    short8 ah1 = *(const short8*)(Ahi + (size_t)row1 * DF + kcol);
    short8 al1 = *(const short8*)(Alo + (size_t)row1 * DF + kcol);
#pragma unroll
    for (int nt = 0; nt < 8; nt++) {
      size_t boff = (size_t)(((nt * 4 + kit) * 64 + lane) * 8);
      short8 bh = *(const short8*)(wr + boff);
      short8 bl = *(const short8*)(wr + 16384 + boff);
      acc[0][nt] = __builtin_amdgcn_mfma_f32_16x16x32_bf16(ah0, bh, acc[0][nt], 0, 0, 0);
      acc[0][nt] = __builtin_amdgcn_mfma_f32_16x16x32_bf16(ah0, bl, acc[0][nt], 0, 0, 0);
      acc[0][nt] = __builtin_amdgcn_mfma_f32_16x16x32_bf16(al0, bh, acc[0][nt], 0, 0, 0);
      acc[1][nt] = __builtin_amdgcn_mfma_f32_16x16x32_bf16(ah1, bh, acc[1][nt], 0, 0, 0);
      acc[1][nt] = __builtin_amdgcn_mfma_f32_16x16x32_bf16(ah1, bl, acc[1][nt], 0, 0, 0);
      acc[1][nt] = __builtin_amdgcn_mfma_f32_16x16x32_bf16(al1, bh, acc[1][nt], 0, 0, 0);
    }
  }

  // store: row = mbase + mt*16 + quad*4 + reg, col = nt*16 + l15
#pragma unroll
  for (int mt = 0; mt < 2; mt++) {
    int rbase = mbase + mt * 16 + quad * 4;
#pragma unroll
    for (int reg = 0; reg < 4; reg++) {
      int row = rbase + reg;
      if (row < N) {
        float* orow = out + (size_t)row * DF + l15;
#pragma unroll
        for (int nt = 0; nt < 8; nt++) orow[nt * 16] = acc[mt][nt][reg];
      }
    }
  }
}

// ---------------------------------------------------------------------------
// CSR build helpers
// ---------------------------------------------------------------------------
__global__ __launch_bounds__(256) void k_zero(int* __restrict__ deg,
                                              int* __restrict__ cur, int N) {
  int i = blockIdx.x * 256 + threadIdx.x;
  if (i < N) { deg[i] = 0; cur[i] = 0; }
}

__global__ __launch_bounds__(256) void k_hist(const int* __restrict__ dst,
                                              int* __restrict__ deg, int E) {
  int e = blockIdx.x * 256 + threadIdx.x;
  if (e < E) atomicAdd(&deg[dst[e]], 1);
}

__global__ __launch_bounds__(256) void k_scan1(const int* __restrict__ deg,
                                               int* __restrict__ excl,
                                               int* __restrict__ bsum, int N) {
  __shared__ int s[256];
  int tid = threadIdx.x;
  int i = blockIdx.x * 256 + tid;
  int v = (i < N) ? deg[i] : 0;
  s[tid] = v;
  __syncthreads();
  for (int d = 1; d < 256; d <<= 1) {
    int t = (tid >= d) ? s[tid - d] : 0;
    __syncthreads();
    s[tid] += t;
    __syncthreads();
  }
  int incl = s[tid];
  if (i < N) excl[i] = incl - v;
  if (tid == 255) bsum[blockIdx.x] = incl;
}

__global__ __launch_bounds__(256) void k_scan2(int* __restrict__ bsum, int nb) {
  __shared__ int s[256];
  __shared__ int carry;
  int tid = threadIdx.x;
  if (tid == 0) carry = 0;
  __syncthreads();
  for (int base = 0; base < nb; base += 256) {
    int i = base + tid;
    int v = (i < nb) ? bsum[i] : 0;
    s[tid] = v;
    __syncthreads();
    for (int d = 1; d < 256; d <<= 1) {
      int t = (tid >= d) ? s[tid - d] : 0;
      __syncthreads();
      s[tid] += t;
      __syncthreads();
    }
    int incl = s[tid];
    int c = carry;
    if (i < nb) bsum[i] = incl - v + c;
    __syncthreads();
    if (tid == 255) carry = c + s[255];
    __syncthreads();
  }
}

__global__ __launch_bounds__(256) void k_scan3(const int* __restrict__ excl,
                                               const int* __restrict__ bsum,
                                               int* __restrict__ off, int N, int E) {
  int i = blockIdx.x * 256 + threadIdx.x;
  if (i < N) off[i] = excl[i] + bsum[blockIdx.x];
  if (i == 0) off[N] = E;
}

__global__ __launch_bounds__(256) void k_fill(const int* __restrict__ dst,
                                              const int* __restrict__ off,
                                              int* __restrict__ cur,
                                              int* __restrict__ eid, int E) {
  int e = blockIdx.x * 256 + threadIdx.x;
  if (e >= E) return;
  int d = dst[e];
  int p = atomicAdd(&cur[d], 1);
  eid[off[d] + p] = e;
}

// ---------------------------------------------------------------------------
// att: one wave per edge. att[e] = dot(t_r, tanh(h_r + efeat[e])). No atomics.
// ---------------------------------------------------------------------------
__global__ __launch_bounds__(256) void att_kernel(const float* __restrict__ proj,
                                                  const float* __restrict__ efeat,
                                                  const int* __restrict__ src,
                                                  const int* __restrict__ dst,
                                                  const int* __restrict__ etype,
                                                  float* __restrict__ att,
                                                  int E, long long rstride, int rsel) {
  int gid = blockIdx.x * 256 + threadIdx.x;
  int e = gid >> 6, lane = gid & 63;
  if (e >= E) return;
  int rt = etype[e];
  if (rsel >= 0 && rt != rsel) return;
  int s = src[e], d = dst[e];
  const float* pb = proj + (size_t)rt * (size_t)rstride;
  float2 tv = ((const float2*)(pb + (size_t)s * DF))[lane];
  float2 hv = ((const float2*)(pb + (size_t)d * DF))[lane];
  float2 ev = ((const float2*)(efeat + (size_t)e * DF))[lane];
  float p = tv.x * tanhf(hv.x + ev.x) + tv.y * tanhf(hv.y + ev.y);
  p += __shfl_down(p, 32);
  p += __shfl_down(p, 16);
  p += __shfl_down(p, 8);
  p += __shfl_down(p, 4);
  p += __shfl_down(p, 2);
  p += __shfl_down(p, 1);
  if (lane == 0) att[e] = p;
}

// ---------------------------------------------------------------------------
// gather: one wave per dst node. Segment softmax + weighted sum, no atomics.
// ---------------------------------------------------------------------------
__global__ __launch_bounds__(256) void gather_kernel(const int* __restrict__ eid,
                                                     const int* __restrict__ off,
                                                     const int* __restrict__ src,
                                                     const float* __restrict__ att,
                                                     const float* __restrict__ nfeat,
                                                     float* __restrict__ h_nb, int N) {
  int node = blockIdx.x * 4 + (threadIdx.x >> 6);
  int lane = threadIdx.x & 63;
  if (node >= N) return;
  int s0 = off[node], s1 = off[node + 1];

  float m = -3.402823466e+38f;
  for (int j = s0 + lane; j < s1; j += 64) {
    float a = att[eid[j]];
    m = fmaxf(m, a);
  }
#pragma unroll
  for (int d = 32; d >= 1; d >>= 1) m = fmaxf(m, __shfl_xor(m, d));

  float2 acc = make_float2(0.f, 0.f);
  float ssum = 0.f;
  for (int j = s0; j < s1; j++) {
    int e = eid[j];
    float ex = expf(att[e] - m);
    int sv = src[e];
    float2 hv = ((const float2*)(nfeat + (size_t)sv * DF))[lane];
    acc.x += hv.x * ex;
    acc.y += hv.y * ex;
    ssum += ex;
  }
  float inv = (s1 > s0) ? 1.0f / ssum : 0.0f;
  float2 o = make_float2(acc.x * inv, acc.y * inv);
  ((float2*)(h_nb + (size_t)node * DF))[lane] = o;
}

// ---------------------------------------------------------------------------
// output GEMM: out[n,j] (op)= lrelu( sum_d A[n,d] * W[j,d] )
// ---------------------------------------------------------------------------
__global__ __launch_bounds__(256) void out_gemm(const float* __restrict__ nfeat,
                                                const float* __restrict__ h_nb,
                                                const float* __restrict__ W,
                                                float* __restrict__ out, int N, int mode) {
  __shared__ float Ws[DF * 129];
  __shared__ float As[32 * DF];
  int n0 = blockIdx.x * 32;
  int t = threadIdx.x;
#pragma unroll
  for (int i = 0; i < 16; i++) {
    int idx = i * 256 + t;
    int j = idx >> 5, d4 = idx & 31;
    float4 v = ((const float4*)W)[idx];
    int b = j * 129 + d4 * 4;
    Ws[b + 0] = v.x; Ws[b + 1] = v.y; Ws[b + 2] = v.z; Ws[b + 3] = v.w;
  }
#pragma unroll
  for (int i = 0; i < 4; i++) {
    int idx = i * 256 + t;
    int row = idx >> 5, c4 = idx & 31;
    int n = n0 + row;
    float4 a = make_float4(0.f, 0.f, 0.f, 0.f);
    if (n < N) {
      float4 hv = ((const float4*)(nfeat + (size_t)n * DF))[c4];
      float4 bv = ((const float4*)(h_nb + (size_t)n * DF))[c4];
      if (mode == 0) a = make_float4(hv.x + bv.x, hv.y + bv.y, hv.z + bv.z, hv.w + bv.w);
      else           a = make_float4(hv.x * bv.x, hv.y * bv.y, hv.z * bv.z, hv.w * bv.w);
    }
    ((float4*)As)[idx] = a;
  }
  __syncthreads();

  int tc = t & 31, tr = t >> 5;
  float acc[4][4] = {};
#pragma unroll 4
  for (int k = 0; k < DF; k++) {
    float a0 = As[(tr * 4 + 0) * DF + k];
    float a1 = As[(tr * 4 + 1) * DF + k];
    float a2 = As[(tr * 4 + 2) * DF + k];
    float a3 = As[(tr * 4 + 3) * DF + k];
    float w0 = Ws[(tc * 4 + 0) * 129 + k];
    float w1 = Ws[(tc * 4 + 1) * 129 + k];
    float w2 = Ws[(tc * 4 + 2) * 129 + k];
    float w3 = Ws[(tc * 4 + 3) * 129 + k];
    acc[0][0] += a0 * w0; acc[0][1] += a0 * w1; acc[0][2] += a0 * w2; acc[0][3] += a0 * w3;
    acc[1][0] += a1 * w0; acc[1][1] += a1 * w1; acc[1][2] += a1 * w2; acc[1][3] += a1 * w3;
    acc[2][0] += a2 * w0; acc[2][1] += a2 * w1; acc[2][2] += a2 * w2; acc[2][3] += a2 * w3;
    acc[3][0] += a3 * w0; acc[3][1] += a3 * w1; acc[3][2] += a3 * w2; acc[3][3] += a3 * w3;
  }
#pragma unroll
  for (int i = 0; i < 4; i++) {
    int n = n0 + tr * 4 + i;
    if (n < N) {
      float4 o = make_float4(lrelu(acc[i][0]), lrelu(acc[i][1]),
                             lrelu(acc[i][2]), lrelu(acc[i][3]));
      float4* po = (float4*)&out[(size_t)n * DF + tc * 4];
      if (mode == 0) {
        *po = o;
      } else {
        float4 old = *po;
        *po = make_float4(old.x + o.x, old.y + o.y, old.z + o.z, old.w + o.w);
      }
    }
  }
}

extern "C" void kernel_launch(void* const* d_in, const int* in_sizes, int n_in,
                              void* d_out, int out_size, void* d_ws, size_t ws_size,
                              hipStream_t stream) {
  const float* nfeat  = (const float*)d_in[0];
  const float* efeat  = (const float*)d_in[1];
  const float* relW   = (const float*)d_in[2];
  const float* W_res  = (const float*)d_in[3];
  const float* W_res2 = (const float*)d_in[4];
  const int*   src    = (const int*)d_in[5];
  const int*   dst    = (const int*)d_in[6];
  const int*   etype  = (const int*)d_in[7];
  float* out = (float*)d_out;

  int N = in_sizes[0] / DF;
  int E = in_sizes[5];
  int R = in_sizes[2] / (DF * DF);

  int nblk256 = (N + 255) / 256;
  int eblk256 = (E + 255) / 256;

  // workspace layout
  char* w = (char*)d_ws;
  float* att  = (float*)w;  w += (size_t)E * 4;
  int*   eid  = (int*)w;    w += (size_t)E * 4;
  int*   deg  = (int*)w;    w += (size_t)N * 4;
  int*   excl = (int*)w;    w += (size_t)N * 4;
  int*   cur  = (int*)w;    w += (size_t)N * 4;
  int*   off  = (int*)w;    w += (size_t)(N + 1) * 4;
  int*   bsum = (int*)w;    w += (size_t)(nblk256 + 1) * 4;
  w = (char*)(((size_t)w + 255) & ~(size_t)255);
  unsigned short* Ahi = (unsigned short*)w; w += (size_t)N * DF * 2;
  unsigned short* Alo = (unsigned short*)w; w += (size_t)N * DF * 2;
  unsigned short* Wsw = (unsigned short*)w; w += (size_t)R * 32768 * 2;
  w = (char*)(((size_t)w + 255) & ~(size_t)255);
  float* h_nb = (float*)w;  w += (size_t)N * DF * 4;
  float* proj = (float*)w;
  size_t used = (size_t)(w - (char*)d_ws);
  size_t proj_full_bytes = (size_t)R * N * DF * 4;
  bool full = (ws_size >= used + proj_full_bytes);

  int row_tiles  = (N + 31) / 32;
  int mfma_tiles = (N + 127) / 128;
  int att_blocks = (E + 3) / 4;
  int gat_blocks = (N + 3) / 4;

  // --- bf16 split conversions ---
  int a4 = N * DF / 4;
  k_convA<<<(a4 + 255) / 256, 256, 0, stream>>>(nfeat, Ahi, Alo, a4);
  int wgrp = R * 8 * 4 * 64;
  k_convW<<<(wgrp + 255) / 256, 256, 0, stream>>>(relW, Wsw, R);

  // --- CSR build ---
  k_zero<<<nblk256, 256, 0, stream>>>(deg, cur, N);
  k_hist<<<eblk256, 256, 0, stream>>>(dst, deg, E);
  k_scan1<<<nblk256, 256, 0, stream>>>(deg, excl, bsum, N);
  k_scan2<<<1, 256, 0, stream>>>(bsum, nblk256);
  k_scan3<<<nblk256, 256, 0, stream>>>(excl, bsum, off, N, E);
  k_fill<<<eblk256, 256, 0, stream>>>(dst, off, cur, eid, E);

  // --- projection (split-bf16 MFMA) + attention logits ---
  if (full) {
    proj_mfma<<<dim3(mfma_tiles, R), 256, 0, stream>>>(Ahi, Alo, Wsw, proj, N, 0,
                                                       (long long)N * DF);
    att_kernel<<<att_blocks, 256, 0, stream>>>(proj, efeat, src, dst, etype, att,
                                               E, (long long)N * DF, -1);
  } else {
    for (int r = 0; r < R; r++) {
      proj_mfma<<<dim3(mfma_tiles, 1), 256, 0, stream>>>(Ahi, Alo, Wsw, proj, N, r, 0);
      att_kernel<<<att_blocks, 256, 0, stream>>>(proj, efeat, src, dst, etype, att,
                                                 E, 0, r);
    }
  }

  // --- segment softmax + message aggregation ---
  gather_kernel<<<gat_blocks, 256, 0, stream>>>(eid, off, src, att, nfeat, h_nb, N);

  // --- output projections ---
  out_gemm<<<row_tiles, 256, 0, stream>>>(nfeat, h_nb, W_res,  out, N, 0);
  out_gemm<<<row_tiles, 256, 0, stream>>>(nfeat, h_nb, W_res2, out, N, 1);
}